// Round 4
// baseline (384.529 us; speedup 1.0000x reference)
//
#include <hip/hip_runtime.h>

typedef unsigned short u16;
typedef unsigned int u32;
typedef __bf16 bf16x8 __attribute__((ext_vector_type(8)));
typedef float floatx4 __attribute__((ext_vector_type(4)));

#define EPS   1e-5f
#define LEAK  0.01f

// ---- conv tiling: block = 128 co x (4h x 32w) = 128 x 128 ----
#define IN_H   6
#define IN_W   34
#define NPOS   (IN_H * IN_W)       // 204 halo positions
#define CPAD   72                  // 64 ci + 8 pad -> 144B row, 16B aligned

__device__ __forceinline__ u16 f2bf(float f) {
    union { float f; u32 i; } v; v.f = f;
    u32 i = v.i;
    return (u16)((i + 0x7fffu + ((i >> 16) & 1u)) >> 16);   // RNE
}
__device__ __forceinline__ bf16x8 ld_frag(const u16* p) {
    uint4 d = *(const uint4*)p;
    return __builtin_bit_cast(bf16x8, d);
}

// ---------------------------------------------------------------------------
// W: [128 co][64 ci][3][3] f32 -> Wt: [9 r][128 co][64 ci] bf16 (147 KB in ws)
// ---------------------------------------------------------------------------
__global__ __launch_bounds__(256) void transpose_w(const float* __restrict__ w,
                                                   u16* __restrict__ wt)
{
    int idx = blockIdx.x * 256 + threadIdx.x;   // 73728 total
    int r   = idx >> 13;
    int rem = idx & 8191;                       // co*64 + ci
    wt[idx] = f2bf(w[rem * 9 + r]);
}

// ---------------------------------------------------------------------------
// Fused: NCHW f32 staging (+bf16 cvt) + implicit-GEMM MFMA conv + BN +
// LeakyReLU + mask. Block 256 thr (4 waves), tile 128co x 128n (4h x 32w).
// Wave (mi,ni): co in [mi*64,+64), n in [ni*64,+64), acc[4][4].
// K = 576 = 18 chunks of 32 (k = r*64 + ci); A-frags prefetched 1 kc ahead.
// __launch_bounds__(256,3): cap regs ~170 -> 3 waves/SIMD, 3 blocks/CU.
// ---------------------------------------------------------------------------
__global__ __launch_bounds__(256, 3) void conv_mfma(
    const float* __restrict__ x,  const u16* __restrict__ wt,
    const float* __restrict__ gamma, const float* __restrict__ beta,
    const float* __restrict__ mean,  const float* __restrict__ var,
    const int* __restrict__ mask, float* __restrict__ out)
{
    __shared__ float s_scale[128];
    __shared__ float s_shift[128];
    __shared__ __attribute__((aligned(16))) u16 s_tile[NPOS * CPAD];

    const int tid = threadIdx.x;
    const int bid = blockIdx.x;
    const int oh0 = (bid >> 4) << 2;    // 128 h-tiles of 4
    const int ow0 = (bid & 15) << 5;    // 16 w-tiles of 32

    if (tid < 128) {
        float sc = gamma[tid] * rsqrtf(var[tid] + EPS);
        s_scale[tid] = sc;
        s_shift[tid] = beta[tid] - mean[tid] * sc;
    }

    // ---- staging: 6x34 halo, 64 ci, straight from NCHW f32 ----
    // item i = cb*204 + pos: consecutive lanes -> consecutive spatial pos
    // -> each of the 8 per-item loads is coalesced (~136B row segments).
    // LDS write: b128 at word-addr pos*36 + cb*4 -> 2-way banked (free).
    #pragma unroll
    for (int it = 0; it < 7; ++it) {
        int i = it * 256 + tid;
        if (i < NPOS * 8) {
            int cb  = i / NPOS;
            int pos = i - cb * NPOS;
            int ihl = pos / IN_W;
            int iwl = pos - ihl * IN_W;
            int sh = oh0 - 1 + ihl; sh = sh < 0 ? -sh : (sh > 511 ? 1022 - sh : sh);
            int sw = ow0 - 1 + iwl; sw = sw < 0 ? -sw : (sw > 511 ? 1022 - sw : sw);
            const float* src = x + (((size_t)cb << 21)) + (sh << 9) + sw; // cb*8 planes
            float v0 = src[0 << 18], v1 = src[1 << 18], v2 = src[2 << 18],
                  v3 = src[3 << 18], v4 = src[4 << 18], v5 = src[5 << 18],
                  v6 = src[6 << 18], v7 = src[7 << 18];
            uint4 p;
            p.x = (u32)f2bf(v0) | ((u32)f2bf(v1) << 16);
            p.y = (u32)f2bf(v2) | ((u32)f2bf(v3) << 16);
            p.z = (u32)f2bf(v4) | ((u32)f2bf(v5) << 16);
            p.w = (u32)f2bf(v6) | ((u32)f2bf(v7) << 16);
            *(uint4*)(s_tile + pos * CPAD + (cb << 3)) = p;
        }
    }
    __syncthreads();

    const int wave = tid >> 6;
    const int lane = tid & 63;
    const int quad = lane >> 4;
    const int l16  = lane & 15;
    const int mi   = wave >> 1;     // co 64-block
    const int ni   = wave & 1;      // n  64-block

    floatx4 acc[4][4];
    #pragma unroll
    for (int i = 0; i < 4; ++i)
        #pragma unroll
        for (int j = 0; j < 4; ++j)
            acc[i][j] = (floatx4){0.f, 0.f, 0.f, 0.f};

    // B-fragment LDS base per n-subtile (at kh=kw=0, ci = quad*8)
    int bbase[4];
    #pragma unroll
    for (int ns = 0; ns < 4; ++ns) {
        int n = ni * 64 + ns * 16 + l16;                 // n = h*32 + w
        bbase[ns] = ((n >> 5) * IN_W + (n & 31)) * CPAD + quad * 8;
    }
    // A-fragment global base: Wt[(r*128 + co)*64 + ci]
    const u16* wbase = wt + (mi << 12) + (l16 << 6) + quad * 8;

    // prefetch A-frags for kc=0
    bf16x8 af_next[4];
    #pragma unroll
    for (int cs = 0; cs < 4; ++cs)
        af_next[cs] = ld_frag(wbase + (cs << 10));

    #pragma unroll 1
    for (int kc = 0; kc < 18; ++kc) {
        const int r    = kc >> 1;
        const int kh   = r / 3;
        const int kw   = r - kh * 3;
        const int cib  = (kc & 1) << 5;
        const int boff = (kh * IN_W + kw) * CPAD + cib;

        bf16x8 af[4];
        #pragma unroll
        for (int cs = 0; cs < 4; ++cs) af[cs] = af_next[cs];

        if (kc < 17) {
            const int kc1  = kc + 1;
            const int r1   = kc1 >> 1;
            const int cib1 = (kc1 & 1) << 5;
            #pragma unroll
            for (int cs = 0; cs < 4; ++cs)
                af_next[cs] = ld_frag(wbase + r1 * 8192 + (cs << 10) + cib1);
        }

        bf16x8 bfr[4];
        #pragma unroll
        for (int ns = 0; ns < 4; ++ns)
            bfr[ns] = ld_frag(s_tile + bbase[ns] + boff);

        #pragma unroll
        for (int cs = 0; cs < 4; ++cs)
            #pragma unroll
            for (int ns = 0; ns < 4; ++ns)
                acc[cs][ns] = __builtin_amdgcn_mfma_f32_16x16x32_bf16(
                    af[cs], bfr[ns], acc[cs][ns], 0, 0, 0);
    }

    // ---- epilogue: BN + LeakyReLU + mask, f32 nontemporal store ----
    // C/D layout: col(n) = lane&15, row(co) = quad*4 + reg
    int nbase[4];
    #pragma unroll
    for (int ns = 0; ns < 4; ++ns) {
        int n = ni * 64 + ns * 16 + l16;
        nbase[ns] = ((oh0 + (n >> 5)) << 9) + ow0 + (n & 31);
    }
    #pragma unroll
    for (int cs = 0; cs < 4; ++cs) {
        const int co0 = mi * 64 + cs * 16 + quad * 4;
        #pragma unroll
        for (int reg = 0; reg < 4; ++reg) {
            const int co = co0 + reg;
            const float sc = s_scale[co], sh = s_shift[co];
            const int cbase = co << 18;
            #pragma unroll
            for (int ns = 0; ns < 4; ++ns) {
                int idx = cbase + nbase[ns];
                int m = __builtin_nontemporal_load(&mask[idx]);
                float y = acc[cs][ns][reg] * sc + sh;
                y = (y >= 0.f) ? y : LEAK * y;
                y = m ? y : 0.f;
                __builtin_nontemporal_store(y, &out[idx]);
            }
        }
    }
}

extern "C" void kernel_launch(void* const* d_in, const int* in_sizes, int n_in,
                              void* d_out, int out_size, void* d_ws, size_t ws_size,
                              hipStream_t stream)
{
    (void)in_sizes; (void)n_in; (void)out_size; (void)ws_size;
    const float* x     = (const float*)d_in[0];
    const float* W     = (const float*)d_in[1];
    const float* gamma = (const float*)d_in[2];
    const float* beta  = (const float*)d_in[3];
    const float* mean  = (const float*)d_in[4];
    const float* var   = (const float*)d_in[5];
    const int*   mask  = (const int*)d_in[6];
    float* out = (float*)d_out;

    u16* wt = (u16*)d_ws;   // 147 KB

    transpose_w<<<288, 256, 0, stream>>>(W, wt);
    conv_mfma<<<2048, 256, 0, stream>>>(x, wt, gamma, beta, mean, var, mask, out);
}

// Round 6
// 348.995 us; speedup vs baseline: 1.1018x; 1.1018x over previous
//
#include <hip/hip_runtime.h>

typedef unsigned short u16;
typedef unsigned int u32;
typedef __bf16 bf16x8 __attribute__((ext_vector_type(8)));
typedef float floatx4 __attribute__((ext_vector_type(4)));
typedef int   intx4   __attribute__((ext_vector_type(4)));

#define EPS   1e-5f
#define LEAK  0.01f

// ---- conv tiling: block = 128 co x (4h x 32w) = 128 x 128 ----
#define IN_H   6
#define IN_W   34
#define NPOS   (IN_H * IN_W)       // 204 halo positions
#define CPAD   72                  // 64 ci + 8 pad -> 144B row, 16B aligned
#define CROW   132                 // f32 C-buffer row pad (mod4=0, bank shift 4)

#define XT_BYTES ((size_t)512 * 512 * 64 * 2)

__device__ __forceinline__ u16 f2bf(float f) {
    union { float f; u32 i; } v; v.f = f;
    u32 i = v.i;
    return (u16)((i + 0x7fffu + ((i >> 16) & 1u)) >> 16);   // RNE
}
__device__ __forceinline__ bf16x8 ld_frag(const u16* p) {
    uint4 d = *(const uint4*)p;
    return __builtin_bit_cast(bf16x8, d);
}

// ---------------------------------------------------------------------------
// x: [64][512][512] f32 (NCHW) -> xt: [512][512][64] bf16 (channels-last)
// ---------------------------------------------------------------------------
__global__ __launch_bounds__(256) void transpose_x(const float* __restrict__ x,
                                                   u16* __restrict__ xt)
{
    __shared__ u32 t[64][65];
    const int tid = threadIdx.x;
    const int s0  = blockIdx.x << 6;      // 64 consecutive spatial positions

    #pragma unroll
    for (int it = 0; it < 4; ++it) {
        int idx = it * 256 + tid;         // 1024 float4 loads: 64ci x 64w
        int ci = idx >> 4, wq = idx & 15;
        float4 d = *(const float4*)(x + (ci << 18) + s0 + (wq << 2));
        u32* row = &t[ci][wq << 2];
        row[0] = f2bf(d.x); row[1] = f2bf(d.y);
        row[2] = f2bf(d.z); row[3] = f2bf(d.w);
    }
    __syncthreads();
    #pragma unroll
    for (int it = 0; it < 2; ++it) {
        int idx = it * 256 + tid;         // 512 vec8 stores
        int sl = idx >> 3, cb = idx & 7;  // spatial-local, ci-block
        uint4 o;
        o.x = t[cb * 8 + 0][sl] | (t[cb * 8 + 1][sl] << 16);
        o.y = t[cb * 8 + 2][sl] | (t[cb * 8 + 3][sl] << 16);
        o.z = t[cb * 8 + 4][sl] | (t[cb * 8 + 5][sl] << 16);
        o.w = t[cb * 8 + 6][sl] | (t[cb * 8 + 7][sl] << 16);
        *(uint4*)(xt + ((s0 + sl) << 6) + (cb << 3)) = o;
    }
}

// ---------------------------------------------------------------------------
// W: [128 co][64 ci][3][3] f32 -> Wt: [9 r][128 co][64 ci] bf16
// ---------------------------------------------------------------------------
__global__ __launch_bounds__(256) void transpose_w(const float* __restrict__ w,
                                                   u16* __restrict__ wt)
{
    int idx = blockIdx.x * 256 + threadIdx.x;   // 73728 total
    int r   = idx >> 13;
    int rem = idx & 8191;                       // co*64 + ci
    wt[idx] = f2bf(w[rem * 9 + r]);
}

// ---------------------------------------------------------------------------
// Implicit-GEMM conv + BN + LeakyReLU + mask. Block 256 thr (4 waves),
// tile 128co x 128n (4h x 32w). Wave (mi,ni): co [mi*64,+64), n [ni*64,+64).
// K = 576 = 18 chunks of 32; A-frags prefetched 1 kc ahead.
// Epilogue: C-tile through LDS (2 chunks 64co x 128n) -> float4/int4
// fully-coalesced mask+store.
// ---------------------------------------------------------------------------
__global__ __launch_bounds__(256, 4) void conv_mfma(
    const u16* __restrict__ xt,   const u16* __restrict__ wt,
    const float* __restrict__ gamma, const float* __restrict__ beta,
    const float* __restrict__ mean,  const float* __restrict__ var,
    const int* __restrict__ mask, float* __restrict__ out)
{
    __shared__ float s_scale[128];
    __shared__ float s_shift[128];
    // union: staging tile (29376 B) / C-buffer 64x132 f32 (33792 B)
    __shared__ __attribute__((aligned(16))) char smem[64 * CROW * 4];
    u16*   s_tile = (u16*)smem;
    float* cbuf   = (float*)smem;

    const int tid = threadIdx.x;
    const int bid = blockIdx.x;
    const int oh0 = (bid >> 4) << 2;    // 128 h-tiles of 4
    const int ow0 = (bid & 15) << 5;    // 16 w-tiles of 32

    if (tid < 128) {
        float sc = gamma[tid] * rsqrtf(var[tid] + EPS);
        s_scale[tid] = sc;
        s_shift[tid] = beta[tid] - mean[tid] * sc;
    }

    // stage 6x34 halo tile from channels-last bf16 xt (1632 b128 loads)
    #pragma unroll
    for (int it = 0; it < 7; ++it) {
        int idx = it * 256 + tid;
        if (idx < NPOS * 8) {
            int pos = idx >> 3, cb = idx & 7;
            int ihl = pos / IN_W;
            int iwl = pos - ihl * IN_W;
            int sh = oh0 - 1 + ihl; sh = sh < 0 ? -sh : (sh > 511 ? 1022 - sh : sh);
            int sw = ow0 - 1 + iwl; sw = sw < 0 ? -sw : (sw > 511 ? 1022 - sw : sw);
            uint4 d = *(const uint4*)(xt + (((sh << 9) + sw) << 6) + (cb << 3));
            *(uint4*)(s_tile + pos * CPAD + (cb << 3)) = d;
        }
    }
    __syncthreads();

    const int wave = tid >> 6;
    const int lane = tid & 63;
    const int quad = lane >> 4;
    const int l16  = lane & 15;
    const int mi   = wave >> 1;     // co 64-block
    const int ni   = wave & 1;      // n  64-block

    floatx4 acc[4][4];
    #pragma unroll
    for (int i = 0; i < 4; ++i)
        #pragma unroll
        for (int j = 0; j < 4; ++j)
            acc[i][j] = (floatx4){0.f, 0.f, 0.f, 0.f};

    // B-fragment LDS base per n-subtile (at kh=kw=0, ci = quad*8)
    int bbase[4];
    #pragma unroll
    for (int ns = 0; ns < 4; ++ns) {
        int n = ni * 64 + ns * 16 + l16;                 // n = h*32 + w
        bbase[ns] = ((n >> 5) * IN_W + (n & 31)) * CPAD + quad * 8;
    }
    // A-fragment global base: Wt[(r*128 + co)*64 + ci]
    const u16* wbase = wt + (mi << 12) + (l16 << 6) + quad * 8;

    bf16x8 af_next[4];
    #pragma unroll
    for (int cs = 0; cs < 4; ++cs)
        af_next[cs] = ld_frag(wbase + (cs << 10));

    #pragma unroll 1
    for (int kc = 0; kc < 18; ++kc) {
        const int r    = kc >> 1;
        const int kh   = r / 3;
        const int kw   = r - kh * 3;
        const int cib  = (kc & 1) << 5;
        const int boff = (kh * IN_W + kw) * CPAD + cib;

        bf16x8 af[4];
        #pragma unroll
        for (int cs = 0; cs < 4; ++cs) af[cs] = af_next[cs];

        if (kc < 17) {
            const int kc1  = kc + 1;
            const int r1   = kc1 >> 1;
            const int cib1 = (kc1 & 1) << 5;
            #pragma unroll
            for (int cs = 0; cs < 4; ++cs)
                af_next[cs] = ld_frag(wbase + r1 * 8192 + (cs << 10) + cib1);
        }

        bf16x8 bfr[4];
        #pragma unroll
        for (int ns = 0; ns < 4; ++ns)
            bfr[ns] = ld_frag(s_tile + bbase[ns] + boff);

        #pragma unroll
        for (int cs = 0; cs < 4; ++cs)
            #pragma unroll
            for (int ns = 0; ns < 4; ++ns)
                acc[cs][ns] = __builtin_amdgcn_mfma_f32_16x16x32_bf16(
                    af[cs], bfr[ns], acc[cs][ns], 0, 0, 0);
    }

    __syncthreads();   // all LDS B-reads done; cbuf may overwrite s_tile

    // ---- epilogue: 2 chunks of 64co x 128n through LDS ----
    // write: row = mi*32 + j*16 + quad*4 + reg, col n = ni*64 + ns*16 + l16
    // read:  idx -> row = idx>>5, v = idx&31 (float4 col), co = (row>>5)*64
    //        + c*32 + (row&31); n = 4v -> h = v>>3, w4 = (v&7)*4
    #pragma unroll
    for (int c = 0; c < 2; ++c) {
        #pragma unroll
        for (int j = 0; j < 2; ++j) {
            const int cs  = c * 2 + j;
            const int row = mi * 32 + j * 16 + quad * 4;
            #pragma unroll
            for (int ns = 0; ns < 4; ++ns) {
                const int n = ni * 64 + ns * 16 + l16;
                float* p = cbuf + row * CROW + n;
                #pragma unroll
                for (int reg = 0; reg < 4; ++reg)
                    p[reg * CROW] = acc[cs][ns][reg];
            }
        }
        __syncthreads();
        #pragma unroll
        for (int k = 0; k < 8; ++k) {
            const int idx = k * 256 + tid;
            const int row = idx >> 5;
            const int v   = idx & 31;
            floatx4 y4 = *(const floatx4*)(cbuf + row * CROW + (v << 2));
            const int co = ((row >> 5) << 6) + (c << 5) + (row & 31);
            const float sc = s_scale[co], sh = s_shift[co];
            const int gidx = (co << 18) + ((oh0 + (v >> 3)) << 9) + ow0 + ((v & 7) << 2);
            intx4 m = __builtin_nontemporal_load((const intx4*)(mask + gidx));
            floatx4 o;
            float t0 = y4.x * sc + sh; o.x = m.x ? fmaxf(t0, t0 * LEAK) : 0.f;
            float t1 = y4.y * sc + sh; o.y = m.y ? fmaxf(t1, t1 * LEAK) : 0.f;
            float t2 = y4.z * sc + sh; o.z = m.z ? fmaxf(t2, t2 * LEAK) : 0.f;
            float t3 = y4.w * sc + sh; o.w = m.w ? fmaxf(t3, t3 * LEAK) : 0.f;
            __builtin_nontemporal_store(o, (floatx4*)(out + gidx));
        }
        if (c == 0) __syncthreads();
    }
}

extern "C" void kernel_launch(void* const* d_in, const int* in_sizes, int n_in,
                              void* d_out, int out_size, void* d_ws, size_t ws_size,
                              hipStream_t stream)
{
    (void)in_sizes; (void)n_in; (void)out_size; (void)ws_size;
    const float* x     = (const float*)d_in[0];
    const float* W     = (const float*)d_in[1];
    const float* gamma = (const float*)d_in[2];
    const float* beta  = (const float*)d_in[3];
    const float* mean  = (const float*)d_in[4];
    const float* var   = (const float*)d_in[5];
    const int*   mask  = (const int*)d_in[6];
    float* out = (float*)d_out;

    u16* xt = (u16*)d_ws;
    u16* wt = (u16*)((char*)d_ws + XT_BYTES);

    transpose_w<<<288, 256, 0, stream>>>(W, wt);
    transpose_x<<<4096, 256, 0, stream>>>(x, xt);
    conv_mfma<<<2048, 256, 0, stream>>>(xt, wt, gamma, beta, mean, var, mask, out);
}